// Round 6
// baseline (98.500 us; speedup 1.0000x reference)
//
#include <hip/hip_runtime.h>

#define BB 32
#define QQ 16384
#define GG 128
#define KK 32
#define NN 9
#define TT 4      // GTs per block; one tail wave per GT
#define TH 512    // 8 waves per block; 1024 blocks -> 8192 waves = 100% occ
#define RR (QQ / TH)  // 32 elements per per-thread range
#define CAP 256   // per-GT candidate capacity (expected ~45)
#define ACAP 256  // per-GT active-range capacity (expected ~33)

typedef unsigned long long u64;
typedef unsigned int u32;

#define INFF __uint_as_float(0x7F800000u)

// packed ascending key: (float bits of nonneg key) << 32 | idx
// lexicographic u64 compare == (value asc, index asc) == jax top_k tie rule
__device__ __forceinline__ u64 pack_asc(float key, u32 idx) {
  return (((u64)__float_as_uint(key)) << 32) | (u64)idx;
}

// EXACT reference squared distance: ((dx^2+dy^2)+dz^2)+dw^2, no contraction.
// ref d = sqrtf(this).
__device__ __forceinline__ float dist2_ref(const float4 g, const float4 p) {
#pragma clang fp contract(off)
  float dx = g.x - p.x;
  float dy = g.y - p.y;
  float dz = g.z - p.z;
  float dw = g.w - p.w;
  float s = dx * dx + dy * dy;
  s = s + dz * dz;
  s = s + dw * dw;
  return s;
}

// IoU exactly as reference (cxcywh -> xyxy, clip, same op order)
__device__ __forceinline__ float iou_ref(const float4 g, const float4 p) {
#pragma clang fp contract(off)
  float gx1 = g.x - 0.5f * g.z, gy1 = g.y - 0.5f * g.w;
  float gx2 = g.x + 0.5f * g.z, gy2 = g.y + 0.5f * g.w;
  float px1 = p.x - 0.5f * p.z, py1 = p.y - 0.5f * p.w;
  float px2 = p.x + 0.5f * p.z, py2 = p.y + 0.5f * p.w;
  float ltx = fmaxf(gx1, px1), lty = fmaxf(gy1, py1);
  float rbx = fminf(gx2, px2), rby = fminf(gy2, py2);
  float wx = fmaxf(rbx - ltx, 0.0f), wy = fmaxf(rby - lty, 0.0f);
  float inter = wx * wy;
  float aa = (gx2 - gx1) * (gy2 - gy1);
  float ab = (px2 - px1) * (py2 - py1);
  return inter / ((aa + ab) - inter);
}

// full ascending bitonic sort across one 64-lane wave, u64 keys
__device__ __forceinline__ u64 bitonic64(u64 v, int lane) {
#pragma unroll
  for (int k = 2; k <= 64; k <<= 1) {
#pragma unroll
    for (int j = k >> 1; j > 0; j >>= 1) {
      u64 o = __shfl_xor(v, j, 64);
      bool up = ((lane & k) == 0);
      bool lower = ((lane & j) == 0);
      v = (lower == up) ? (v < o ? v : o) : (v > o ? v : o);
    }
  }
  return v;
}

// full ascending bitonic sort across one 64-lane wave, float keys
// (handles negatives; values finite or +inf padding, never NaN)
__device__ __forceinline__ float bitonic64f(float v, int lane) {
#pragma unroll
  for (int k = 2; k <= 64; k <<= 1) {
#pragma unroll
    for (int j = k >> 1; j > 0; j >>= 1) {
      float o = __shfl_xor(v, j, 64);
      bool up = ((lane & k) == 0);
      bool lower = ((lane & j) == 0);
      v = (lower == up) ? fminf(v, o) : fmaxf(v, o);
    }
  }
  return v;
}

__global__ __launch_bounds__(TH, 8) void atss_kernel(
    const float4* __restrict__ pred, const float4* __restrict__ gtb,
    int* __restrict__ out) {
  __shared__ float smin[TT][TH];            // 8 KB: per-GT range mins
  __shared__ float ckey[TT][CAP];           // 4 KB: candidate d2
  __shared__ unsigned short cidx[TT][CAP];  // 2 KB: candidate indices
  __shared__ unsigned short sact[TT][ACAP]; // 2 KB: active range ids
  __shared__ int kidx[TT][KK];              // 512 B
  __shared__ int nC[TT];
  __shared__ int nAct[TT];

  const int t = threadIdx.x;
  // XCD-aware swizzle (assumed round-robin block->XCD): all 32 blocks of a
  // batch share one XCD so the 256 KB pred slice lives in that XCD's L2.
  const int f = blockIdx.x;
  const int b = (f & 7) * 4 + (f >> 8);
  const int g0 = ((f >> 3) & 31) * TT;

  if (t < TT) {
    nC[t] = 0;
    nAct[t] = 0;
  }

  // 4 GT boxes from block-uniform addresses -> scalar loads / SGPRs
  float4 G[TT];
#pragma unroll
  for (int gg = 0; gg < TT; ++gg) G[gg] = gtb[b * GG + g0 + gg];

  const float4* pb = pred + (size_t)b * QQ;

  // ---- pass 1: per-thread min of s = |p|^2 - 2 g.p over 32 elements ----
  // (d2 shifted by the per-GT constant -|g|^2 -> same ordering)
  float mn[TT];
#pragma unroll
  for (int gg = 0; gg < TT; ++gg) mn[gg] = INFF;
  float4 p = pb[t];
#pragma unroll
  for (int j = 0; j < RR; ++j) {
    float4 pn = p;
    if (j + 1 < RR) pn = pb[t + (j + 1) * TH];  // prefetch next
    float pp = fmaf(p.x, p.x, fmaf(p.y, p.y, fmaf(p.z, p.z, p.w * p.w)));
#pragma unroll
    for (int gg = 0; gg < TT; ++gg) {
      float dot = fmaf(G[gg].x, p.x,
                  fmaf(G[gg].y, p.y,
                  fmaf(G[gg].z, p.z, G[gg].w * p.w)));
      mn[gg] = fminf(mn[gg], fmaf(-2.0f, dot, pp));
    }
    p = pn;
  }
#pragma unroll
  for (int gg = 0; gg < TT; ++gg) smin[gg][t] = mn[gg];

  __syncthreads();  // the ONLY block-wide barrier

  const int w = t >> 6;
  const int lane = t & 63;
  if (w >= TT) return;  // waves TT..7 done; frees wave slots

  // ================= wave w handles GT (g0 + w) alone =================
  const float4 gt = gtb[b * GG + g0 + w];  // wave-uniform reload

  // ---- threshold: merge 512 range-mins -> 64 lane-mins, sort, take the
  // 32nd smallest U_s. Each lane-min covers 8 disjoint 32-elem ranges, so
  // >=32 distinct elements have approx s <= U_s. Inflation covers fma-form
  // vs ref-form rounding (~5e-7 abs) and sqrt-collapse ties.
  float a = INFF;
#pragma unroll
  for (int k = 0; k < TH / 64; ++k) a = fminf(a, smin[w][lane + k * 64]);
  float srt = bitonic64f(a, lane);
  float Us = __shfl(srt, 31, 64);  // 32nd smallest, wave-uniform
  float gg2 = fmaf(gt.x, gt.x,
              fmaf(gt.y, gt.y, fmaf(gt.z, gt.z, gt.w * gt.w)));
  const float sUs = Us + fabsf(Us) * 2e-5f + 4e-6f;          // s-space test
  const float T = fmaxf(Us + gg2, 0.0f) * 1.00002f + 4e-6f;  // d2-space test

  // ---- compact active ranges (expected ~33 of 512) into wave-local list
#pragma unroll
  for (int k = 0; k < TH / 64; ++k) {
    int r = lane + k * 64;
    if (smin[w][r] <= sUs) {
      int pos = atomicAdd(&nAct[w], 1);
      if (pos < ACAP) sact[w][pos] = (unsigned short)r;
    }
  }
  int na = nAct[w];  // same-wave DS ordering: no barrier needed

  // ---- exact-d2 collection over active ranges ----
  if (na <= ACAP) {
    for (int it = lane; it < na; it += 64) {
      int r = sact[w][it];
      for (int j = 0; j < RR; ++j) {
        int i = r + j * TH;
        float d2 = dist2_ref(gt, pb[i]);
        if (d2 <= T) {
          int pos = atomicAdd(&nC[w], 1);
          if (pos < CAP) {
            ckey[w][pos] = d2;
            cidx[w][pos] = (unsigned short)i;
          }
        }
      }
    }
  } else {
    // pathological: dense wave rescan of all 512 ranges
    for (int r = lane; r < TH; r += 64) {
      for (int j = 0; j < RR; ++j) {
        int i = r + j * TH;
        float d2 = dist2_ref(gt, pb[i]);
        if (d2 <= T) {
          int pos = atomicAdd(&nC[w], 1);
          if (pos < CAP) {
            ckey[w][pos] = d2;
            cidx[w][pos] = (unsigned short)i;
          }
        }
      }
    }
  }
  int n = nC[w];  // >= 32 guaranteed by the bound argument

  // ---- select top-32 by (d, idx) ascending; d = sqrtf(d2) on the fly.
  // IEEE sqrtf (no fast-math) == jnp.sqrt bitwise.
  if (n > CAP) {
    // pathological-only exact serial fallback
    if (lane == 0) {
      u64 best[KK];
      for (int l = 0; l < KK; ++l) best[l] = ~0ull;
      for (int i = 0; i < QQ; ++i) {
        float d = sqrtf(dist2_ref(gt, pb[i]));
        u64 pk = pack_asc(d, (u32)i);
        if (pk < best[KK - 1]) {
          int pos = KK - 1;
          while (pos > 0 && best[pos - 1] > pk) {
            best[pos] = best[pos - 1];
            --pos;
          }
          best[pos] = pk;
        }
      }
      for (int l = 0; l < KK; ++l) kidx[w][l] = (int)(best[l] & 0xFFFFFFFFull);
    }
  } else if (n <= 64) {
    // fast path (expected ~99%): one wave bitonic sort
    u64 v = (lane < n) ? pack_asc(sqrtf(ckey[w][lane]), (u32)cidx[w][lane])
                       : ~0ull;
    u64 s = bitonic64(v, lane);
    if (lane < KK) kidx[w][lane] = (int)(s & 0xFFFFFFFFull);
  } else {
    // 64 < n <= CAP: 32 rounds of wave-wide argmin extraction
    volatile float* vk = ckey[w];
    for (int sel = 0; sel < KK; ++sel) {
      u64 lm = ~0ull;
      int ls = -1;
      for (int s = lane; s < n; s += 64) {
        float d = sqrtf(vk[s]);  // sqrtf(inf)=inf for consumed slots
        u64 pk = pack_asc(d, (u32)cidx[w][s]);
        if (pk < lm) {
          lm = pk;
          ls = s;
        }
      }
      u64 ww = lm;
#pragma unroll
      for (int j = 32; j > 0; j >>= 1) {
        u64 o = __shfl_xor(ww, j, 64);
        ww = o < ww ? o : ww;
      }
      if (lm == ww && ls >= 0) {  // unique winner (idx unique)
        vk[ls] = INFF;            // mark used
        kidx[w][sel] = (int)(ww & 0xFFFFFFFFull);
      }
    }
  }
  // same-wave DS ordering: kidx[w] writes visible to this wave's reads

  // ---- IoU of the 32 candidates, top-9 by (iou desc, position asc) ----
  {
    u64 v = ~0ull;
    if (lane < KK) {
      float iou = iou_ref(gt, pb[kidx[w][lane]]);
      // ~bits(iou) strictly decreasing in iou (iou >= 0): ascending packed
      // sort == descending iou, ties -> lower K-position first
      v = (((u64)(~__float_as_uint(iou))) << 32) | (u64)lane;
    }
    u64 s = bitonic64(v, lane);
    if (lane < NN) {
      int pos = (int)(s & 0xFFFFFFFFull);
      int base = (b * GG + g0 + w) * NN + lane;
      out[base] = kidx[w][pos];           // pred_idx
      out[BB * GG * NN + base] = g0 + w;  // gt_idx
    }
  }
}

extern "C" void kernel_launch(void* const* d_in, const int* in_sizes, int n_in,
                              void* d_out, int out_size, void* d_ws, size_t ws_size,
                              hipStream_t stream) {
  (void)in_sizes;
  (void)n_in;
  (void)out_size;
  (void)d_ws;
  (void)ws_size;
  const float4* pred = (const float4*)d_in[0];  // [B, Q, 4] f32
  const float4* gt = (const float4*)d_in[1];    // [B, G, 4] f32
  int* out = (int*)d_out;                       // [2 * B * G * N] int32
  atss_kernel<<<(GG / TT) * BB, TH, 0, stream>>>(pred, gt, out);
}

// Round 7
// 95.450 us; speedup vs baseline: 1.0320x; 1.0320x over previous
//
#include <hip/hip_runtime.h>

#define BB 32
#define QQ 16384
#define GG 128
#define KK 32
#define NN 9
#define TT 16     // GTs per block == waves per block (wave w owns GT g0+w)
#define TH 1024   // 16 waves; 256 blocks -> 1 block/CU, 4096 waves
#define RR (QQ / TH)  // 16 elements per thread
#define NW (TH / 64)  // 16 waves
#define CAP 256   // per-GT candidate capacity (expected ~45)
#define ACAP 128  // per-GT active-range capacity (expected ~35)
#define UF 4      // load prefetch batch

typedef unsigned long long u64;
typedef unsigned int u32;

#define INFF __uint_as_float(0x7F800000u)

// packed ascending key: (float bits of nonneg key) << 32 | idx
// lexicographic u64 compare == (value asc, index asc) == jax top_k tie rule
__device__ __forceinline__ u64 pack_asc(float key, u32 idx) {
  return (((u64)__float_as_uint(key)) << 32) | (u64)idx;
}

// EXACT reference squared distance: ((dx^2+dy^2)+dz^2)+dw^2, no contraction.
// ref d = sqrtf(this).
__device__ __forceinline__ float dist2_ref(const float4 g, const float4 p) {
#pragma clang fp contract(off)
  float dx = g.x - p.x;
  float dy = g.y - p.y;
  float dz = g.z - p.z;
  float dw = g.w - p.w;
  float s = dx * dx + dy * dy;
  s = s + dz * dz;
  s = s + dw * dw;
  return s;
}

// IoU exactly as reference (cxcywh -> xyxy, clip, same op order)
__device__ __forceinline__ float iou_ref(const float4 g, const float4 p) {
#pragma clang fp contract(off)
  float gx1 = g.x - 0.5f * g.z, gy1 = g.y - 0.5f * g.w;
  float gx2 = g.x + 0.5f * g.z, gy2 = g.y + 0.5f * g.w;
  float px1 = p.x - 0.5f * p.z, py1 = p.y - 0.5f * p.w;
  float px2 = p.x + 0.5f * p.z, py2 = p.y + 0.5f * p.w;
  float ltx = fmaxf(gx1, px1), lty = fmaxf(gy1, py1);
  float rbx = fminf(gx2, px2), rby = fminf(gy2, py2);
  float wx = fmaxf(rbx - ltx, 0.0f), wy = fmaxf(rby - lty, 0.0f);
  float inter = wx * wy;
  float aa = (gx2 - gx1) * (gy2 - gy1);
  float ab = (px2 - px1) * (py2 - py1);
  return inter / ((aa + ab) - inter);
}

// full ascending bitonic sort across one 64-lane wave, u64 keys
__device__ __forceinline__ u64 bitonic64(u64 v, int lane) {
#pragma unroll
  for (int k = 2; k <= 64; k <<= 1) {
#pragma unroll
    for (int j = k >> 1; j > 0; j >>= 1) {
      u64 o = __shfl_xor(v, j, 64);
      bool up = ((lane & k) == 0);
      bool lower = ((lane & j) == 0);
      v = (lower == up) ? (v < o ? v : o) : (v > o ? v : o);
    }
  }
  return v;
}

// full ascending bitonic sort across one 64-lane wave, float keys
// (handles negatives; values finite or +inf padding, never NaN)
__device__ __forceinline__ float bitonic64f(float v, int lane) {
#pragma unroll
  for (int k = 2; k <= 64; k <<= 1) {
#pragma unroll
    for (int j = k >> 1; j > 0; j >>= 1) {
      float o = __shfl_xor(v, j, 64);
      bool up = ((lane & k) == 0);
      bool lower = ((lane & j) == 0);
      v = (lower == up) ? fminf(v, o) : fmaxf(v, o);
    }
  }
  return v;
}

__global__ __launch_bounds__(TH, 4) void atss_kernel(
    const float4* __restrict__ pred, const float4* __restrict__ gtb,
    int* __restrict__ out) {
  __shared__ float smin[TT][TH];            // 64 KB: per-(GT,thread) range mins
  __shared__ float ckey[TT][CAP];           // 16 KB: candidate d2
  __shared__ unsigned short cidx[TT][CAP];  // 8 KB: candidate indices
  __shared__ unsigned short sact[TT][ACAP]; // 4 KB: active range ids
  __shared__ int kidx[TT][KK];              // 2 KB
  __shared__ int nC[TT];
  __shared__ int nAct[TT];

  const int t = threadIdx.x;
  // XCD swizzle (round-robin block->XCD assumed): f%8 == b%8 so all 8
  // g-chunks of one batch share an XCD; its L2 holds that 256 KB slice.
  const int f = blockIdx.x;
  const int b = (f & 7) | ((f >> 6) << 3);
  const int g0 = ((f >> 3) & 7) * TT;

  if (t < TT) {
    nC[t] = 0;
    nAct[t] = 0;
  }

  // 16 GT boxes from block-uniform addresses -> scalar loads / SGPRs
  float4 G[TT];
#pragma unroll
  for (int gg = 0; gg < TT; ++gg) G[gg] = gtb[b * GG + g0 + gg];

  const float4* pb = pred + (size_t)b * QQ;

  // ---- pass 1: per-thread min of s = |p|^2 - 2 g.p over RR elements ----
  // (d2 shifted by per-GT constant -|g|^2 -> same ordering). One float4
  // load feeds 16 GTs (~84 VALU); 4 loads kept in flight.
  float mn[TT];
#pragma unroll
  for (int gg = 0; gg < TT; ++gg) mn[gg] = INFF;

  float4 P[UF];
#pragma unroll
  for (int u = 0; u < UF; ++u) P[u] = pb[t + u * TH];
#pragma unroll
  for (int j = 0; j < RR; j += UF) {
    float4 C[UF];
#pragma unroll
    for (int u = 0; u < UF; ++u) C[u] = P[u];
    if (j + UF < RR) {
#pragma unroll
      for (int u = 0; u < UF; ++u) P[u] = pb[t + (j + UF + u) * TH];
    }
#pragma unroll
    for (int u = 0; u < UF; ++u) {
      float4 p = C[u];
      float pp = fmaf(p.x, p.x, fmaf(p.y, p.y, fmaf(p.z, p.z, p.w * p.w)));
#pragma unroll
      for (int gg = 0; gg < TT; ++gg) {
        float dot = fmaf(G[gg].x, p.x,
                    fmaf(G[gg].y, p.y,
                    fmaf(G[gg].z, p.z, G[gg].w * p.w)));
        mn[gg] = fminf(mn[gg], fmaf(-2.0f, dot, pp));
      }
    }
  }
#pragma unroll
  for (int gg = 0; gg < TT; ++gg) smin[gg][t] = mn[gg];

  __syncthreads();  // the ONLY block-wide barrier

  const int w = t >> 6;   // wave id == GT slot (NW == TT)
  const int lane = t & 63;

  // ================= wave w handles GT (g0 + w) alone =================
  const float4 gt = gtb[b * GG + g0 + w];  // wave-uniform reload

  // ---- threshold: merge TH range-mins -> 64 lane-mins, sort, take the
  // 32nd smallest U_s. Lane-mins cover disjoint element sets, so >=32
  // distinct elements have approx s <= U_s. Inflation covers fma-form vs
  // ref-form rounding (~5e-7 abs) and sqrt-collapse ties.
  float a = INFF;
#pragma unroll
  for (int k = 0; k < NW; ++k) a = fminf(a, smin[w][lane + k * 64]);
  float srt = bitonic64f(a, lane);
  float Us = __shfl(srt, 31, 64);  // 32nd smallest, wave-uniform
  float gg2 = fmaf(gt.x, gt.x,
              fmaf(gt.y, gt.y, fmaf(gt.z, gt.z, gt.w * gt.w)));
  const float sUs = Us + fabsf(Us) * 2e-5f + 4e-6f;          // s-space test
  const float T = fmaxf(Us + gg2, 0.0f) * 1.00002f + 4e-6f;  // d2-space test

  // ---- compact active ranges (expected ~35 of 1024) into wave-local list
#pragma unroll
  for (int k = 0; k < NW; ++k) {
    int r = lane + k * 64;
    if (smin[w][r] <= sUs) {
      int pos = atomicAdd(&nAct[w], 1);
      if (pos < ACAP) sact[w][pos] = (unsigned short)r;
    }
  }
  int na = nAct[w];  // same-wave DS ordering: no barrier needed

  // ---- exact-d2 collection over active ranges ----
  if (na <= ACAP) {
    for (int it = lane; it < na; it += 64) {
      int r = sact[w][it];
      for (int j = 0; j < RR; ++j) {
        int i = r + j * TH;
        float d2 = dist2_ref(gt, pb[i]);
        if (d2 <= T) {
          int pos = atomicAdd(&nC[w], 1);
          if (pos < CAP) {
            ckey[w][pos] = d2;
            cidx[w][pos] = (unsigned short)i;
          }
        }
      }
    }
  } else {
    // pathological: dense wave rescan of all ranges
    for (int r = lane; r < TH; r += 64) {
      for (int j = 0; j < RR; ++j) {
        int i = r + j * TH;
        float d2 = dist2_ref(gt, pb[i]);
        if (d2 <= T) {
          int pos = atomicAdd(&nC[w], 1);
          if (pos < CAP) {
            ckey[w][pos] = d2;
            cidx[w][pos] = (unsigned short)i;
          }
        }
      }
    }
  }
  int n = nC[w];  // >= 32 guaranteed by the bound argument

  // ---- select top-32 by (d, idx) ascending; d = sqrtf(d2) on the fly.
  // IEEE sqrtf (no fast-math) == jnp.sqrt bitwise.
  if (n > CAP) {
    // pathological-only exact serial fallback
    if (lane == 0) {
      u64 best[KK];
      for (int l = 0; l < KK; ++l) best[l] = ~0ull;
      for (int i = 0; i < QQ; ++i) {
        float d = sqrtf(dist2_ref(gt, pb[i]));
        u64 pk = pack_asc(d, (u32)i);
        if (pk < best[KK - 1]) {
          int pos = KK - 1;
          while (pos > 0 && best[pos - 1] > pk) {
            best[pos] = best[pos - 1];
            --pos;
          }
          best[pos] = pk;
        }
      }
      for (int l = 0; l < KK; ++l) kidx[w][l] = (int)(best[l] & 0xFFFFFFFFull);
    }
  } else if (n <= 64) {
    // fast path (expected ~99%): one wave bitonic sort
    u64 v = (lane < n) ? pack_asc(sqrtf(ckey[w][lane]), (u32)cidx[w][lane])
                       : ~0ull;
    u64 s = bitonic64(v, lane);
    if (lane < KK) kidx[w][lane] = (int)(s & 0xFFFFFFFFull);
  } else {
    // 64 < n <= CAP: 32 rounds of wave-wide argmin extraction
    volatile float* vk = ckey[w];
    for (int sel = 0; sel < KK; ++sel) {
      u64 lm = ~0ull;
      int ls = -1;
      for (int s = lane; s < n; s += 64) {
        float d = sqrtf(vk[s]);  // sqrtf(inf)=inf for consumed slots
        u64 pk = pack_asc(d, (u32)cidx[w][s]);
        if (pk < lm) {
          lm = pk;
          ls = s;
        }
      }
      u64 ww = lm;
#pragma unroll
      for (int j = 32; j > 0; j >>= 1) {
        u64 o = __shfl_xor(ww, j, 64);
        ww = o < ww ? o : ww;
      }
      if (lm == ww && ls >= 0) {  // unique winner (idx unique)
        vk[ls] = INFF;            // mark used
        kidx[w][sel] = (int)(ww & 0xFFFFFFFFull);
      }
    }
  }
  // same-wave DS ordering: kidx[w] writes visible to this wave's reads

  // ---- IoU of the 32 candidates, top-9 by (iou desc, position asc) ----
  {
    u64 v = ~0ull;
    if (lane < KK) {
      float iou = iou_ref(gt, pb[kidx[w][lane]]);
      // ~bits(iou) strictly decreasing in iou (iou >= 0): ascending packed
      // sort == descending iou, ties -> lower K-position first
      v = (((u64)(~__float_as_uint(iou))) << 32) | (u64)lane;
    }
    u64 s = bitonic64(v, lane);
    if (lane < NN) {
      int pos = (int)(s & 0xFFFFFFFFull);
      int base = (b * GG + g0 + w) * NN + lane;
      out[base] = kidx[w][pos];           // pred_idx
      out[BB * GG * NN + base] = g0 + w;  // gt_idx
    }
  }
}

extern "C" void kernel_launch(void* const* d_in, const int* in_sizes, int n_in,
                              void* d_out, int out_size, void* d_ws, size_t ws_size,
                              hipStream_t stream) {
  (void)in_sizes;
  (void)n_in;
  (void)out_size;
  (void)d_ws;
  (void)ws_size;
  const float4* pred = (const float4*)d_in[0];  // [B, Q, 4] f32
  const float4* gt = (const float4*)d_in[1];    // [B, G, 4] f32
  int* out = (int*)d_out;                       // [2 * B * G * N] int32
  atss_kernel<<<(GG / TT) * BB, TH, 0, stream>>>(pred, gt, out);
}

// Round 8
// 91.385 us; speedup vs baseline: 1.0779x; 1.0445x over previous
//
#include <hip/hip_runtime.h>

#define BB 32
#define QQ 16384
#define GG 128
#define KK 32
#define NN 9

// ---- kernel A geometry ----
#define TTA 8      // GTs per A-block
#define THA 1024   // threads per A-block
#define RRA (QQ / THA)  // 16 elements per thread-range
#define UF 4       // load prefetch batch

// ---- kernel B geometry ----
#define THB 512    // 8 waves per B-block; one wave per (b,g)
#define NWB (THB / 64)
#define CAPB 192   // per-wave candidate capacity (expected ~45)
#define ACAPB 64   // per-wave active-range capacity (expected ~40)

typedef unsigned long long u64;
typedef unsigned int u32;

#define INFF __uint_as_float(0x7F800000u)

// packed ascending key: (float bits of nonneg key) << 32 | idx
// lexicographic u64 compare == (value asc, index asc) == jax top_k tie rule
__device__ __forceinline__ u64 pack_asc(float key, u32 idx) {
  return (((u64)__float_as_uint(key)) << 32) | (u64)idx;
}

// EXACT reference squared distance: ((dx^2+dy^2)+dz^2)+dw^2, no contraction.
// ref d = sqrtf(this).
__device__ __forceinline__ float dist2_ref(const float4 g, const float4 p) {
#pragma clang fp contract(off)
  float dx = g.x - p.x;
  float dy = g.y - p.y;
  float dz = g.z - p.z;
  float dw = g.w - p.w;
  float s = dx * dx + dy * dy;
  s = s + dz * dz;
  s = s + dw * dw;
  return s;
}

// IoU exactly as reference (cxcywh -> xyxy, clip, same op order)
__device__ __forceinline__ float iou_ref(const float4 g, const float4 p) {
#pragma clang fp contract(off)
  float gx1 = g.x - 0.5f * g.z, gy1 = g.y - 0.5f * g.w;
  float gx2 = g.x + 0.5f * g.z, gy2 = g.y + 0.5f * g.w;
  float px1 = p.x - 0.5f * p.z, py1 = p.y - 0.5f * p.w;
  float px2 = p.x + 0.5f * p.z, py2 = p.y + 0.5f * p.w;
  float ltx = fmaxf(gx1, px1), lty = fmaxf(gy1, py1);
  float rbx = fminf(gx2, px2), rby = fminf(gy2, py2);
  float wx = fmaxf(rbx - ltx, 0.0f), wy = fmaxf(rby - lty, 0.0f);
  float inter = wx * wy;
  float aa = (gx2 - gx1) * (gy2 - gy1);
  float ab = (px2 - px1) * (py2 - py1);
  return inter / ((aa + ab) - inter);
}

// full ascending bitonic sort across one 64-lane wave, u64 keys
__device__ __forceinline__ u64 bitonic64(u64 v, int lane) {
#pragma unroll
  for (int k = 2; k <= 64; k <<= 1) {
#pragma unroll
    for (int j = k >> 1; j > 0; j >>= 1) {
      u64 o = __shfl_xor(v, j, 64);
      bool up = ((lane & k) == 0);
      bool lower = ((lane & j) == 0);
      v = (lower == up) ? (v < o ? v : o) : (v > o ? v : o);
    }
  }
  return v;
}

// full ascending bitonic sort across one 64-lane wave, float keys
// (handles negatives; values finite or +inf padding, never NaN)
__device__ __forceinline__ float bitonic64f(float v, int lane) {
#pragma unroll
  for (int k = 2; k <= 64; k <<= 1) {
#pragma unroll
    for (int j = k >> 1; j > 0; j >>= 1) {
      float o = __shfl_xor(v, j, 64);
      bool up = ((lane & k) == 0);
      bool lower = ((lane & j) == 0);
      v = (lower == up) ? fminf(v, o) : fmaxf(v, o);
    }
  }
  return v;
}

// block f -> (batch, gt-group) swizzle shared by A and B so both kernels'
// block f lands on the same XCD (round-robin assumed) with the same data.
__device__ __forceinline__ void swz(int f, int& b, int& g0) {
  b = (f & 7) * 4 + (f >> 7);
  g0 = ((f >> 3) & 15) * TTA;
}

// ======================= Kernel A: pure pass 1 =======================
// No LDS, no barriers. Each thread computes, for its 16-element range and
// each of 8 GTs, min s = |p|^2 - 2 g.p (d2 shifted by per-GT const -|g|^2,
// same ordering), and writes it to gsmin[(b*GG+g)*THA + t] (coalesced).
__global__ __launch_bounds__(THA, 4) void pass1_kernel(
    const float4* __restrict__ pred, const float4* __restrict__ gtb,
    float* __restrict__ gsmin) {
  const int t = threadIdx.x;
  int b, g0;
  swz(blockIdx.x, b, g0);

  float4 G[TTA];
#pragma unroll
  for (int gg = 0; gg < TTA; ++gg) G[gg] = gtb[b * GG + g0 + gg];

  const float4* pb = pred + (size_t)b * QQ;

  float mn[TTA];
#pragma unroll
  for (int gg = 0; gg < TTA; ++gg) mn[gg] = INFF;

  float4 P[UF];
#pragma unroll
  for (int u = 0; u < UF; ++u) P[u] = pb[t + u * THA];
#pragma unroll
  for (int j = 0; j < RRA; j += UF) {
    float4 C[UF];
#pragma unroll
    for (int u = 0; u < UF; ++u) C[u] = P[u];
    if (j + UF < RRA) {
#pragma unroll
      for (int u = 0; u < UF; ++u) P[u] = pb[t + (j + UF + u) * THA];
    }
#pragma unroll
    for (int u = 0; u < UF; ++u) {
      float4 p = C[u];
      float pp = fmaf(p.x, p.x, fmaf(p.y, p.y, fmaf(p.z, p.z, p.w * p.w)));
#pragma unroll
      for (int gg = 0; gg < TTA; ++gg) {
        float dot = fmaf(G[gg].x, p.x,
                    fmaf(G[gg].y, p.y,
                    fmaf(G[gg].z, p.z, G[gg].w * p.w)));
        mn[gg] = fminf(mn[gg], fmaf(-2.0f, dot, pp));
      }
    }
  }
#pragma unroll
  for (int gg = 0; gg < TTA; ++gg)
    gsmin[(size_t)(b * GG + g0 + gg) * THA + t] = mn[gg];
}

// ======================= Kernel B: pure tail =======================
// One wave per (b,g); zero barriers; everything wave-local.
__global__ __launch_bounds__(THB, 4) void tail_kernel(
    const float4* __restrict__ pred, const float4* __restrict__ gtb,
    const float* __restrict__ gsmin, int* __restrict__ out) {
  __shared__ float ckey[NWB][CAPB];
  __shared__ unsigned short cidx[NWB][CAPB];
  __shared__ unsigned short sact[NWB][ACAPB];
  __shared__ int kidx[NWB][KK];
  __shared__ int nC[NWB];
  __shared__ int nAct[NWB];

  const int t = threadIdx.x;
  const int w = t >> 6;
  const int lane = t & 63;
  int b, g0;
  swz(blockIdx.x, b, g0);
  const int g = g0 + w;
  const int task = b * GG + g;

  if (lane == 0) {
    nC[w] = 0;
    nAct[w] = 0;
  }
  // same-wave DS ordering: inits visible to this wave's later atomics

  const float4 gt = gtb[task];
  const float4* pb = pred + (size_t)b * QQ;
  const float* sm = gsmin + (size_t)task * THA;

  // ---- load this task's 1024 range-mins: lane owns ranges lane*16..+15
  // (a disjoint partition, which is all the bound argument needs).
  float4 V[4];
#pragma unroll
  for (int m = 0; m < 4; ++m) V[m] = ((const float4*)sm)[lane * 4 + m];
  float a = INFF;
#pragma unroll
  for (int m = 0; m < 4; ++m)
    a = fminf(a, fminf(fminf(V[m].x, V[m].y), fminf(V[m].z, V[m].w)));

  // ---- threshold: sort 64 lane-mins, take the 32nd smallest U_s.
  // Each lane-min covers 256 disjoint elements -> >=32 distinct elements
  // have approx s <= U_s. Inflation covers fma-form vs ref-form rounding
  // (~5e-7 abs) and sqrt-collapse ties (verified margins from R5-R7).
  float srt = bitonic64f(a, lane);
  float Us = __shfl(srt, 31, 64);
  float gg2 = fmaf(gt.x, gt.x,
              fmaf(gt.y, gt.y, fmaf(gt.z, gt.z, gt.w * gt.w)));
  const float sUs = Us + fabsf(Us) * 2e-5f + 4e-6f;          // s-space test
  const float T = fmaxf(Us + gg2, 0.0f) * 1.00002f + 4e-6f;  // d2-space test

  // ---- compact active ranges (expected ~40 of 1024) ----
#pragma unroll
  for (int m = 0; m < 4; ++m) {
    float vv[4] = {V[m].x, V[m].y, V[m].z, V[m].w};
#pragma unroll
    for (int q = 0; q < 4; ++q) {
      if (vv[q] <= sUs) {
        int pos = atomicAdd(&nAct[w], 1);
        if (pos < ACAPB) sact[w][pos] = (unsigned short)(lane * 16 + m * 4 + q);
      }
    }
  }
  int na = nAct[w];

  // ---- exact-d2 collection ----
  if (na <= ACAPB) {
    for (int it = lane; it < na; it += 64) {
      int r = sact[w][it];
      for (int j = 0; j < RRA; ++j) {
        int i = r + j * THA;
        float d2 = dist2_ref(gt, pb[i]);
        if (d2 <= T) {
          int pos = atomicAdd(&nC[w], 1);
          if (pos < CAPB) {
            ckey[w][pos] = d2;
            cidx[w][pos] = (unsigned short)i;
          }
        }
      }
    }
  } else {
    // pathological: dense rescan of all ranges
    for (int r = lane; r < THA; r += 64) {
      for (int j = 0; j < RRA; ++j) {
        int i = r + j * THA;
        float d2 = dist2_ref(gt, pb[i]);
        if (d2 <= T) {
          int pos = atomicAdd(&nC[w], 1);
          if (pos < CAPB) {
            ckey[w][pos] = d2;
            cidx[w][pos] = (unsigned short)i;
          }
        }
      }
    }
  }
  int n = nC[w];  // >= 32 guaranteed by the bound argument

  // ---- select top-32 by (d, idx) ascending; d = sqrtf(d2) (IEEE, == jnp)
  if (n > CAPB) {
    // pathological-only exact serial fallback
    if (lane == 0) {
      u64 best[KK];
      for (int l = 0; l < KK; ++l) best[l] = ~0ull;
      for (int i = 0; i < QQ; ++i) {
        float d = sqrtf(dist2_ref(gt, pb[i]));
        u64 pk = pack_asc(d, (u32)i);
        if (pk < best[KK - 1]) {
          int pos = KK - 1;
          while (pos > 0 && best[pos - 1] > pk) {
            best[pos] = best[pos - 1];
            --pos;
          }
          best[pos] = pk;
        }
      }
      for (int l = 0; l < KK; ++l) kidx[w][l] = (int)(best[l] & 0xFFFFFFFFull);
    }
  } else if (n <= 64) {
    // fast path (expected ~99%): one wave bitonic sort
    u64 v = (lane < n) ? pack_asc(sqrtf(ckey[w][lane]), (u32)cidx[w][lane])
                       : ~0ull;
    u64 s = bitonic64(v, lane);
    if (lane < KK) kidx[w][lane] = (int)(s & 0xFFFFFFFFull);
  } else {
    // 64 < n <= CAPB: 32 rounds of wave-wide argmin extraction
    volatile float* vk = ckey[w];
    for (int sel = 0; sel < KK; ++sel) {
      u64 lm = ~0ull;
      int ls = -1;
      for (int s = lane; s < n; s += 64) {
        float d = sqrtf(vk[s]);  // sqrtf(inf)=inf for consumed slots
        u64 pk = pack_asc(d, (u32)cidx[w][s]);
        if (pk < lm) {
          lm = pk;
          ls = s;
        }
      }
      u64 ww = lm;
#pragma unroll
      for (int j = 32; j > 0; j >>= 1) {
        u64 o = __shfl_xor(ww, j, 64);
        ww = o < ww ? o : ww;
      }
      if (lm == ww && ls >= 0) {  // unique winner (idx unique)
        vk[ls] = INFF;            // mark used
        kidx[w][sel] = (int)(ww & 0xFFFFFFFFull);
      }
    }
  }
  // same-wave DS ordering: kidx[w] writes visible to this wave's reads

  // ---- IoU of the 32 candidates, top-9 by (iou desc, position asc) ----
  {
    u64 v = ~0ull;
    if (lane < KK) {
      float iou = iou_ref(gt, pb[kidx[w][lane]]);
      // ~bits(iou) strictly decreasing in iou (iou >= 0): ascending packed
      // sort == descending iou, ties -> lower K-position first
      v = (((u64)(~__float_as_uint(iou))) << 32) | (u64)lane;
    }
    u64 s = bitonic64(v, lane);
    if (lane < NN) {
      int pos = (int)(s & 0xFFFFFFFFull);
      int base = task * NN + lane;
      out[base] = kidx[w][pos];      // pred_idx
      out[BB * GG * NN + base] = g;  // gt_idx
    }
  }
}

// ============== fused fallback (R7 kernel, proven) for tiny ws ==============
#define TTF 16
#define THF 1024
#define RRF (QQ / THF)
#define NWF (THF / 64)
#define CAPF 256
#define ACAPF 128

__global__ __launch_bounds__(THF, 4) void atss_fused(
    const float4* __restrict__ pred, const float4* __restrict__ gtb,
    int* __restrict__ out) {
  __shared__ float smin[TTF][THF];
  __shared__ float ckey[TTF][CAPF];
  __shared__ unsigned short cidx[TTF][CAPF];
  __shared__ unsigned short sact[TTF][ACAPF];
  __shared__ int kidx[TTF][KK];
  __shared__ int nC[TTF];
  __shared__ int nAct[TTF];

  const int t = threadIdx.x;
  const int f = blockIdx.x;
  const int b = (f & 7) | ((f >> 6) << 3);
  const int g0 = ((f >> 3) & 7) * TTF;

  if (t < TTF) {
    nC[t] = 0;
    nAct[t] = 0;
  }

  float4 G[TTF];
#pragma unroll
  for (int gg = 0; gg < TTF; ++gg) G[gg] = gtb[b * GG + g0 + gg];
  const float4* pb = pred + (size_t)b * QQ;

  float mn[TTF];
#pragma unroll
  for (int gg = 0; gg < TTF; ++gg) mn[gg] = INFF;
  float4 P[UF];
#pragma unroll
  for (int u = 0; u < UF; ++u) P[u] = pb[t + u * THF];
#pragma unroll
  for (int j = 0; j < RRF; j += UF) {
    float4 C[UF];
#pragma unroll
    for (int u = 0; u < UF; ++u) C[u] = P[u];
    if (j + UF < RRF) {
#pragma unroll
      for (int u = 0; u < UF; ++u) P[u] = pb[t + (j + UF + u) * THF];
    }
#pragma unroll
    for (int u = 0; u < UF; ++u) {
      float4 p = C[u];
      float pp = fmaf(p.x, p.x, fmaf(p.y, p.y, fmaf(p.z, p.z, p.w * p.w)));
#pragma unroll
      for (int gg = 0; gg < TTF; ++gg) {
        float dot = fmaf(G[gg].x, p.x,
                    fmaf(G[gg].y, p.y,
                    fmaf(G[gg].z, p.z, G[gg].w * p.w)));
        mn[gg] = fminf(mn[gg], fmaf(-2.0f, dot, pp));
      }
    }
  }
#pragma unroll
  for (int gg = 0; gg < TTF; ++gg) smin[gg][t] = mn[gg];

  __syncthreads();

  const int w = t >> 6;
  const int lane = t & 63;
  const float4 gt = gtb[b * GG + g0 + w];

  float a = INFF;
#pragma unroll
  for (int k = 0; k < NWF; ++k) a = fminf(a, smin[w][lane + k * 64]);
  float srt = bitonic64f(a, lane);
  float Us = __shfl(srt, 31, 64);
  float gg2 = fmaf(gt.x, gt.x,
              fmaf(gt.y, gt.y, fmaf(gt.z, gt.z, gt.w * gt.w)));
  const float sUs = Us + fabsf(Us) * 2e-5f + 4e-6f;
  const float T = fmaxf(Us + gg2, 0.0f) * 1.00002f + 4e-6f;

#pragma unroll
  for (int k = 0; k < NWF; ++k) {
    int r = lane + k * 64;
    if (smin[w][r] <= sUs) {
      int pos = atomicAdd(&nAct[w], 1);
      if (pos < ACAPF) sact[w][pos] = (unsigned short)r;
    }
  }
  int na = nAct[w];

  if (na <= ACAPF) {
    for (int it = lane; it < na; it += 64) {
      int r = sact[w][it];
      for (int j = 0; j < RRF; ++j) {
        int i = r + j * THF;
        float d2 = dist2_ref(gt, pb[i]);
        if (d2 <= T) {
          int pos = atomicAdd(&nC[w], 1);
          if (pos < CAPF) {
            ckey[w][pos] = d2;
            cidx[w][pos] = (unsigned short)i;
          }
        }
      }
    }
  } else {
    for (int r = lane; r < THF; r += 64) {
      for (int j = 0; j < RRF; ++j) {
        int i = r + j * THF;
        float d2 = dist2_ref(gt, pb[i]);
        if (d2 <= T) {
          int pos = atomicAdd(&nC[w], 1);
          if (pos < CAPF) {
            ckey[w][pos] = d2;
            cidx[w][pos] = (unsigned short)i;
          }
        }
      }
    }
  }
  int n = nC[w];

  if (n > CAPF) {
    if (lane == 0) {
      u64 best[KK];
      for (int l = 0; l < KK; ++l) best[l] = ~0ull;
      for (int i = 0; i < QQ; ++i) {
        float d = sqrtf(dist2_ref(gt, pb[i]));
        u64 pk = pack_asc(d, (u32)i);
        if (pk < best[KK - 1]) {
          int pos = KK - 1;
          while (pos > 0 && best[pos - 1] > pk) {
            best[pos] = best[pos - 1];
            --pos;
          }
          best[pos] = pk;
        }
      }
      for (int l = 0; l < KK; ++l) kidx[w][l] = (int)(best[l] & 0xFFFFFFFFull);
    }
  } else if (n <= 64) {
    u64 v = (lane < n) ? pack_asc(sqrtf(ckey[w][lane]), (u32)cidx[w][lane])
                       : ~0ull;
    u64 s = bitonic64(v, lane);
    if (lane < KK) kidx[w][lane] = (int)(s & 0xFFFFFFFFull);
  } else {
    volatile float* vk = ckey[w];
    for (int sel = 0; sel < KK; ++sel) {
      u64 lm = ~0ull;
      int ls = -1;
      for (int s = lane; s < n; s += 64) {
        float d = sqrtf(vk[s]);
        u64 pk = pack_asc(d, (u32)cidx[w][s]);
        if (pk < lm) {
          lm = pk;
          ls = s;
        }
      }
      u64 ww = lm;
#pragma unroll
      for (int j = 32; j > 0; j >>= 1) {
        u64 o = __shfl_xor(ww, j, 64);
        ww = o < ww ? o : ww;
      }
      if (lm == ww && ls >= 0) {
        vk[ls] = INFF;
        kidx[w][sel] = (int)(ww & 0xFFFFFFFFull);
      }
    }
  }

  {
    u64 v = ~0ull;
    if (lane < KK) {
      float iou = iou_ref(gt, pb[kidx[w][lane]]);
      v = (((u64)(~__float_as_uint(iou))) << 32) | (u64)lane;
    }
    u64 s = bitonic64(v, lane);
    if (lane < NN) {
      int pos = (int)(s & 0xFFFFFFFFull);
      int base = (b * GG + g0 + w) * NN + lane;
      out[base] = kidx[w][pos];
      out[BB * GG * NN + base] = g0 + w;
    }
  }
}

extern "C" void kernel_launch(void* const* d_in, const int* in_sizes, int n_in,
                              void* d_out, int out_size, void* d_ws, size_t ws_size,
                              hipStream_t stream) {
  (void)in_sizes;
  (void)n_in;
  (void)out_size;
  const float4* pred = (const float4*)d_in[0];  // [B, Q, 4] f32
  const float4* gt = (const float4*)d_in[1];    // [B, G, 4] f32
  int* out = (int*)d_out;                       // [2 * B * G * N] int32

  const size_t need = (size_t)BB * GG * THA * sizeof(float);  // 16.8 MB
  if (ws_size >= need) {
    float* gsmin = (float*)d_ws;
    pass1_kernel<<<(GG / TTA) * BB, THA, 0, stream>>>(pred, gt, gsmin);
    tail_kernel<<<(GG / TTA) * BB, THB, 0, stream>>>(pred, gt, gsmin, out);
  } else {
    atss_fused<<<(GG / TTF) * BB, THF, 0, stream>>>(pred, gt, out);
  }
}

// Round 9
// 78.765 us; speedup vs baseline: 1.2506x; 1.1602x over previous
//
#include <hip/hip_runtime.h>

#define BB 32
#define QQ 16384
#define GG 128
#define KK 32
#define NN 9
#define TT 8      // GTs per block; tail waves 0..7, waves 8..15 exit early
#define TH 1024   // 16 waves; 512 blocks -> 2 blocks/CU
#define RR (QQ / TH)  // 16 elements per thread-range
#define NW (TH / 64)
#define CAP 192   // per-GT candidate capacity (expected ~40 with tight U)
#define ACAP 96   // per-GT active-range capacity (expected ~36)
#define UF 4      // load prefetch batch

typedef unsigned long long u64;
typedef unsigned int u32;

#define INFF __uint_as_float(0x7F800000u)

// packed ascending key: (float bits of nonneg key) << 32 | idx
// lexicographic u64 compare == (value asc, index asc) == jax top_k tie rule
__device__ __forceinline__ u64 pack_asc(float key, u32 idx) {
  return (((u64)__float_as_uint(key)) << 32) | (u64)idx;
}

// EXACT reference squared distance: ((dx^2+dy^2)+dz^2)+dw^2, no contraction.
// ref d = sqrtf(this).
__device__ __forceinline__ float dist2_ref(const float4 g, const float4 p) {
#pragma clang fp contract(off)
  float dx = g.x - p.x;
  float dy = g.y - p.y;
  float dz = g.z - p.z;
  float dw = g.w - p.w;
  float s = dx * dx + dy * dy;
  s = s + dz * dz;
  s = s + dw * dw;
  return s;
}

// IoU exactly as reference (cxcywh -> xyxy, clip, same op order)
__device__ __forceinline__ float iou_ref(const float4 g, const float4 p) {
#pragma clang fp contract(off)
  float gx1 = g.x - 0.5f * g.z, gy1 = g.y - 0.5f * g.w;
  float gx2 = g.x + 0.5f * g.z, gy2 = g.y + 0.5f * g.w;
  float px1 = p.x - 0.5f * p.z, py1 = p.y - 0.5f * p.w;
  float px2 = p.x + 0.5f * p.z, py2 = p.y + 0.5f * p.w;
  float ltx = fmaxf(gx1, px1), lty = fmaxf(gy1, py1);
  float rbx = fminf(gx2, px2), rby = fminf(gy2, py2);
  float wx = fmaxf(rbx - ltx, 0.0f), wy = fmaxf(rby - lty, 0.0f);
  float inter = wx * wy;
  float aa = (gx2 - gx1) * (gy2 - gy1);
  float ab = (px2 - px1) * (py2 - py1);
  return inter / ((aa + ab) - inter);
}

// full ascending bitonic sort across one 64-lane wave, u64 keys
__device__ __forceinline__ u64 bitonic64(u64 v, int lane) {
#pragma unroll
  for (int k = 2; k <= 64; k <<= 1) {
#pragma unroll
    for (int j = k >> 1; j > 0; j >>= 1) {
      u64 o = __shfl_xor(v, j, 64);
      bool up = ((lane & k) == 0);
      bool lower = ((lane & j) == 0);
      v = (lower == up) ? (v < o ? v : o) : (v > o ? v : o);
    }
  }
  return v;
}

// full ascending bitonic sort across one 64-lane wave, float keys
// (handles negatives; values finite or +inf padding, never NaN)
__device__ __forceinline__ float bitonic64f(float v, int lane) {
#pragma unroll
  for (int k = 2; k <= 64; k <<= 1) {
#pragma unroll
    for (int j = k >> 1; j > 0; j >>= 1) {
      float o = __shfl_xor(v, j, 64);
      bool up = ((lane & k) == 0);
      bool lower = ((lane & j) == 0);
      v = (lower == up) ? fminf(v, o) : fmaxf(v, o);
    }
  }
  return v;
}

__global__ __launch_bounds__(TH, 8) void atss_kernel(
    const float4* __restrict__ pred, const float4* __restrict__ gtb,
    int* __restrict__ out) {
  __shared__ float smin[TT][TH];            // 32 KB
  __shared__ float ckey[TT][CAP];           // 6 KB
  __shared__ unsigned short cidx[TT][CAP];  // 3 KB
  __shared__ unsigned short sact[TT][ACAP]; // 1.5 KB
  __shared__ int kidx[TT][KK];              // 1 KB
  __shared__ int nC[TT];
  __shared__ int nAct[TT];

  const int t = threadIdx.x;
  // XCD swizzle (round-robin block->XCD assumed): the 16 blocks of one
  // batch share an XCD; its L2 holds that batch's 256 KB pred slice.
  const int f = blockIdx.x;
  const int b = (f & 7) * 4 + (f >> 7);
  const int g0 = ((f >> 3) & 15) * TT;

  if (t < TT) {
    nC[t] = 0;
    nAct[t] = 0;
  }

  // 8 GT boxes from block-uniform addresses -> scalar loads / SGPRs
  float4 G[TT];
#pragma unroll
  for (int gg = 0; gg < TT; ++gg) G[gg] = gtb[b * GG + g0 + gg];

  const float4* pb = pred + (size_t)b * QQ;

  // ---- pass 1: per-thread min of s = |p|^2 - 2 g.p over 16 elements ----
  // (d2 shifted by per-GT constant -|g|^2 -> same ordering). One float4
  // load feeds 8 GTs; 4 loads kept in flight.
  float mn[TT];
#pragma unroll
  for (int gg = 0; gg < TT; ++gg) mn[gg] = INFF;

  float4 P[UF];
#pragma unroll
  for (int u = 0; u < UF; ++u) P[u] = pb[t + u * TH];
#pragma unroll
  for (int j = 0; j < RR; j += UF) {
    float4 C[UF];
#pragma unroll
    for (int u = 0; u < UF; ++u) C[u] = P[u];
    if (j + UF < RR) {
#pragma unroll
      for (int u = 0; u < UF; ++u) P[u] = pb[t + (j + UF + u) * TH];
    }
#pragma unroll
    for (int u = 0; u < UF; ++u) {
      float4 p = C[u];
      float pp = fmaf(p.x, p.x, fmaf(p.y, p.y, fmaf(p.z, p.z, p.w * p.w)));
#pragma unroll
      for (int gg = 0; gg < TT; ++gg) {
        float dot = fmaf(G[gg].x, p.x,
                    fmaf(G[gg].y, p.y,
                    fmaf(G[gg].z, p.z, G[gg].w * p.w)));
        mn[gg] = fminf(mn[gg], fmaf(-2.0f, dot, pp));
      }
    }
  }
#pragma unroll
  for (int gg = 0; gg < TT; ++gg) smin[gg][t] = mn[gg];

  __syncthreads();  // the ONLY block-wide barrier

  const int w = t >> 6;
  const int lane = t & 63;
  if (w >= TT) return;  // waves 8..15 done; frees wave slots

  // ================= wave w handles GT (g0 + w) alone =================
  const float4 gt = gtb[b * GG + g0 + w];  // wave-uniform reload

  // ---- load this GT's 1024 thread-mins; lane owns threads {lane + 64k}
  // (conflict-free stride-4B ds reads; a disjoint range partition).
  float V[NW];
#pragma unroll
  for (int k = 0; k < NW; ++k) V[k] = smin[w][lane + 64 * k];

  // ---- per-lane 2 smallest of its 16 values (branchless) ----
  float m1 = INFF, m2 = INFF;
#pragma unroll
  for (int k = 0; k < NW; ++k) {
    float v = V[k];
    float nm1 = fminf(m1, v);
    m2 = fminf(m2, fmaxf(m1, v));
    m1 = nm1;
  }

  // ---- U = 32nd smallest of the 128 kept values (2 per lane) ----
  // Kept set is a subset of the 1024 thread-mins -> its 32nd smallest is
  // >= the true 32nd smallest thread-min; the 32 kept values <= U are 32
  // DISTINCT threads' range-mins -> >= 32 distinct elements have approx
  // s <= U. Far tighter than the old 64-lane-min bound (E[n] ~36 vs ~44,
  // P(n>64) ~0 -> the slow extraction path dies).
  float A = bitonic64f(m1, lane);
  float Bs = bitonic64f(m2, lane);
  float Br = __shfl(Bs, 63 - lane, 64);  // descending B
  float m = fminf(A, Br);  // bitonic sequence holding the 64 smallest
#pragma unroll
  for (int j = 32; j > 0; j >>= 1) {  // sort bitonic -> ascending
    float o = __shfl_xor(m, j, 64);
    m = ((lane & j) == 0) ? fminf(m, o) : fmaxf(m, o);
  }
  float Us = __shfl(m, 31, 64);  // 32nd smallest, wave-uniform
  float gg2 = fmaf(gt.x, gt.x,
              fmaf(gt.y, gt.y, fmaf(gt.z, gt.z, gt.w * gt.w)));
  // Inflation covers fma-form vs ref-form rounding (~5e-7 abs) and
  // sqrt-collapse ties (margins proven in R5-R8).
  const float sUs = Us + fabsf(Us) * 2e-5f + 4e-6f;          // s-space test
  const float T = fmaxf(Us + gg2, 0.0f) * 1.00002f + 4e-6f;  // d2-space test

  // ---- compact active ranges (expected ~36 of 1024) ----
#pragma unroll
  for (int k = 0; k < NW; ++k) {
    if (V[k] <= sUs) {
      int pos = atomicAdd(&nAct[w], 1);
      if (pos < ACAP) sact[w][pos] = (unsigned short)(lane + 64 * k);
    }
  }
  int na = nAct[w];  // same-wave DS ordering: no barrier needed

  // ---- exact-d2 collection over active ranges ----
  if (na <= ACAP) {
    for (int it = lane; it < na; it += 64) {
      int r = sact[w][it];
      for (int j = 0; j < RR; ++j) {
        int i = r + j * TH;
        float d2 = dist2_ref(gt, pb[i]);
        if (d2 <= T) {
          int pos = atomicAdd(&nC[w], 1);
          if (pos < CAP) {
            ckey[w][pos] = d2;
            cidx[w][pos] = (unsigned short)i;
          }
        }
      }
    }
  } else {
    // pathological: dense wave rescan of all ranges
    for (int r = lane; r < TH; r += 64) {
      for (int j = 0; j < RR; ++j) {
        int i = r + j * TH;
        float d2 = dist2_ref(gt, pb[i]);
        if (d2 <= T) {
          int pos = atomicAdd(&nC[w], 1);
          if (pos < CAP) {
            ckey[w][pos] = d2;
            cidx[w][pos] = (unsigned short)i;
          }
        }
      }
    }
  }
  int n = nC[w];  // >= 32 guaranteed by the bound argument

  // ---- select top-32 by (d, idx) ascending; d = sqrtf(d2) (IEEE == jnp)
  if (n > CAP) {
    // pathological-only exact serial fallback
    if (lane == 0) {
      u64 best[KK];
      for (int l = 0; l < KK; ++l) best[l] = ~0ull;
      for (int i = 0; i < QQ; ++i) {
        float d = sqrtf(dist2_ref(gt, pb[i]));
        u64 pk = pack_asc(d, (u32)i);
        if (pk < best[KK - 1]) {
          int pos = KK - 1;
          while (pos > 0 && best[pos - 1] > pk) {
            best[pos] = best[pos - 1];
            --pos;
          }
          best[pos] = pk;
        }
      }
      for (int l = 0; l < KK; ++l) kidx[w][l] = (int)(best[l] & 0xFFFFFFFFull);
    }
  } else if (n <= 64) {
    // fast path (now ~100%): one wave bitonic sort
    u64 v = (lane < n) ? pack_asc(sqrtf(ckey[w][lane]), (u32)cidx[w][lane])
                       : ~0ull;
    u64 s = bitonic64(v, lane);
    if (lane < KK) kidx[w][lane] = (int)(s & 0xFFFFFFFFull);
  } else {
    // 64 < n <= CAP: 32 rounds of wave-wide argmin extraction (rare)
    volatile float* vk = ckey[w];
    for (int sel = 0; sel < KK; ++sel) {
      u64 lm = ~0ull;
      int ls = -1;
      for (int s = lane; s < n; s += 64) {
        float d = sqrtf(vk[s]);  // sqrtf(inf)=inf for consumed slots
        u64 pk = pack_asc(d, (u32)cidx[w][s]);
        if (pk < lm) {
          lm = pk;
          ls = s;
        }
      }
      u64 ww = lm;
#pragma unroll
      for (int j = 32; j > 0; j >>= 1) {
        u64 o = __shfl_xor(ww, j, 64);
        ww = o < ww ? o : ww;
      }
      if (lm == ww && ls >= 0) {  // unique winner (idx unique)
        vk[ls] = INFF;            // mark used
        kidx[w][sel] = (int)(ww & 0xFFFFFFFFull);
      }
    }
  }
  // same-wave DS ordering: kidx[w] writes visible to this wave's reads

  // ---- IoU of the 32 candidates, top-9 by (iou desc, position asc) ----
  {
    u64 v = ~0ull;
    if (lane < KK) {
      float iou = iou_ref(gt, pb[kidx[w][lane]]);
      // ~bits(iou) strictly decreasing in iou (iou >= 0): ascending packed
      // sort == descending iou, ties -> lower K-position first
      v = (((u64)(~__float_as_uint(iou))) << 32) | (u64)lane;
    }
    u64 s = bitonic64(v, lane);
    if (lane < NN) {
      int pos = (int)(s & 0xFFFFFFFFull);
      int base = (b * GG + g0 + w) * NN + lane;
      out[base] = kidx[w][pos];           // pred_idx
      out[BB * GG * NN + base] = g0 + w;  // gt_idx
    }
  }
}

extern "C" void kernel_launch(void* const* d_in, const int* in_sizes, int n_in,
                              void* d_out, int out_size, void* d_ws, size_t ws_size,
                              hipStream_t stream) {
  (void)in_sizes;
  (void)n_in;
  (void)out_size;
  (void)d_ws;
  (void)ws_size;
  const float4* pred = (const float4*)d_in[0];  // [B, Q, 4] f32
  const float4* gt = (const float4*)d_in[1];    // [B, G, 4] f32
  int* out = (int*)d_out;                       // [2 * B * G * N] int32
  atss_kernel<<<(GG / TT) * BB, TH, 0, stream>>>(pred, gt, out);
}